// Round 3
// baseline (289.223 us; speedup 1.0000x reference)
//
#include <hip/hip_runtime.h>

// Grouped GRU: G=64, D=16, H=8, B=64, T=512. One cell per 8 lanes.
//
// R10: kill the register-pressure-induced load sinking.
// Evidence: R8/R9 both 126-131us, VALUBusy 35%, VGPR 172-176. Static live-set
// of the R7/R9 design = xv ring 128 + weights 76 + temps ~30 = ~210 VGPRs,
// but allocator emitted 176 => it must shorten ring lifetimes by SINKING the
// x loads toward their use (volatile asm without memory clobber does not
// block load motion). Prefetch distance collapses -> ~300 cyc exposed
// L2/L3/HBM latency per body = the unexplained stall (590 cyc/step vs ~206
// issue). R9's boundary-collapse was neutral because boundaries were never
// the cost.
// Change: per-lane x loads. Each lane loads only ITS 8B pair of the cell's
// 64B x-row (1 dwordx2/lane/step, wave = 512B contiguous, perfectly
// coalesced; was 4 dwordx4/lane redundant x8). At proj, the octet gathers
// the 8 pairs with the SAME DPP set used for h (xor1/2/3 + half-mirror);
// the resulting jmap permutation is folded into the wih pair order at
// preload (same trick as whh). Ring slot: 16 -> 2 VGPRs; live set ~140.
// Predicted: VGPR ~145, dispatch 126 -> 55-75us, VALUBusy 55-75%.
// If instead ~110-125us at VGPR~145: latency theory wrong too -> pivot to
// forced co-residency (grid 64 x block 512, 2 waves/SIMD).
//
// Carried: packed-fp32 proj (v_pk_fma_f32); gate scales pre-folded into
// weights (-log2e for r,z; +2log2e for n); n-gate b_hh stays inside r*(...)
// per reference (R7 fix); 8-step prefetch ring, proj 2 steps ahead.

#define Gn 64
#define Dn 16
#define Hn 8
#define Tn 512

typedef float v2f __attribute__((ext_vector_type(2)));

__device__ __forceinline__ float rcp_fast(float v) { return __builtin_amdgcn_rcpf(v); }
__device__ __forceinline__ float exp2_fast(float v) { return __builtin_amdgcn_exp2f(v); }

#define KNL (-1.44269504088896340736f)   // -log2(e)
#define KP2 ( 2.88539008177792681472f)   // +2*log2(e)

template <int CTRL>
__device__ __forceinline__ float dppf(float v) {
    return __int_as_float(
        __builtin_amdgcn_update_dpp(0, __float_as_int(v), CTRL, 0xF, 0xF, false));
}
template <int CTRL>
__device__ __forceinline__ v2f dpp2(v2f v) {
    v2f r;
    r.x = dppf<CTRL>(v.x);
    r.y = dppf<CTRL>(v.y);
    return r;
}

__global__ __attribute__((amdgpu_flat_work_group_size(64, 64),
                          amdgpu_waves_per_eu(1, 1)))
void mcgru_kernel(
    const float* __restrict__ x,     // [B, T, G*D]
    const float* __restrict__ W_ih,  // [G, 3H, D]
    const float* __restrict__ W_hh,  // [G, 3H, H]
    const float* __restrict__ b_ih,  // [G, 3H]
    const float* __restrict__ b_hh,  // [G, 3H]
    float* __restrict__ out)         // [B, T, G, H]
{
    const int tid  = blockIdx.x * blockDim.x + threadIdx.x;
    const int cell = tid >> 3;
    const int l    = tid & 7;
    const int g    = cell & (Gn - 1);
    const int b    = cell >> 6;
    const int s4   = l & 3;
    const int q    = l >> 2;

    // DPP gather order: slot k arrives from octet-lane jmap[k] = l ^ mk,
    // mk = {0,1,2,3,7,6,5,4}. Used for BOTH the h gather and the x gather.
    int jmap[8];
#pragma unroll
    for (int k = 0; k < 8; ++k) {
        const int hi2 = k >> 2, r = k & 3;
        jmap[k] = ((q ^ hi2) << 2) | (s4 ^ r ^ (hi2 ? 3 : 0));
    }

    const float scale[3] = {KNL, KNL, KP2};

    // ---- preload weights, pre-scaled, DPP-order permuted ----
    v2f   wih[3][8];    // W_ih pair k = row elems [2*jmap[k], 2*jmap[k]+1], scaled
    float whh[3][8];    // W_hh columns permuted to DPP order, scaled
    float bs[3];        // r,z: (b_ih+b_hh)*KNL ; n: b_ih*KP2 only
    float bhn;          // n-gate: b_hh * KP2, kept under the r-multiplication
#pragma unroll
    for (int qg = 0; qg < 3; ++qg) {
        const int row = qg * Hn + l;
        const float sc = scale[qg];
        const float* wr = W_ih + ((size_t)g * 24 + row) * Dn;
#pragma unroll
        for (int k = 0; k < 8; ++k) {
            const int dp = jmap[k] * 2;
            wih[qg][k] = (v2f){wr[dp] * sc, wr[dp + 1] * sc};
        }
        const float* hrow = W_hh + ((size_t)g * 24 + row) * Hn;
#pragma unroll
        for (int k = 0; k < 8; ++k) whh[qg][k] = hrow[jmap[k]] * sc;
        if (qg < 2) {
            bs[qg] = (b_ih[g * 24 + row] + b_hh[g * 24 + row]) * sc;  // additive fold OK
        } else {
            bs[qg] = b_ih[g * 24 + row] * sc;   // input-side bias only
            bhn    = b_hh[g * 24 + row] * sc;   // stays inside r*(...)
        }
    }
    // Pin weights once, pre-loop: no sink/remat into the T loop.
#pragma unroll
    for (int qg = 0; qg < 3; ++qg) {
#pragma unroll
        for (int i = 0; i < 8; ++i) asm volatile("" : "+v"(wih[qg][i]));
#pragma unroll
        for (int k = 0; k < 8; ++k) asm volatile("" : "+v"(whh[qg][k]));
        asm volatile("" : "+v"(bs[qg]));
    }
    asm volatile("" : "+v"(bhn));

    // Per-lane x pointer: this lane owns bytes [2l, 2l+2) of its cell's row.
    // Wave = 8 cells * 64B = 512B contiguous per step.
    const float* xq = x   + ((size_t)b * Tn * Gn + g) * Dn + 2 * l;
    float*       op = out + ((size_t)b * Tn * Gn + g) * Hn + l;

    auto load_x = [&](int t) -> v2f {
        return *(const v2f*)(xq + (size_t)t * (Gn * Dn));
    };
    // Gather the octet's 8 pairs via DPP, dot with permutation-folded weights.
    auto proj = [&](v2f xv, float* gx) {
        v2f X[8];
        X[0] = xv;
        X[1] = dpp2<0xB1>(xv);    // quad_perm xor1
        X[2] = dpp2<0x4E>(xv);    // quad_perm xor2
        X[3] = dpp2<0x1B>(xv);    // quad_perm xor3
        X[4] = dpp2<0x141>(X[0]); // row_half_mirror = xor7 within octet
        X[5] = dpp2<0x141>(X[1]);
        X[6] = dpp2<0x141>(X[2]);
        X[7] = dpp2<0x141>(X[3]);
#pragma unroll
        for (int qg = 0; qg < 3; ++qg) {
            v2f acc = wih[qg][0] * X[0];
#pragma unroll
            for (int i = 1; i < 8; ++i) acc += wih[qg][i] * X[i];  // v_pk_fma_f32
            gx[qg] = (bs[qg] + acc.x) + acc.y;
        }
    };

    float h = 0.0f;
    auto step = [&](const float* gx, int t) {
        float H[8];
        H[0] = h;
        H[1] = dppf<0xB1>(h);     // quad_perm xor1
        H[2] = dppf<0x4E>(h);     // quad_perm xor2
        H[3] = dppf<0x1B>(h);     // quad_perm xor3
        H[4] = dppf<0x141>(H[0]); // row_half_mirror = xor7 within octet
        H[5] = dppf<0x141>(H[1]);
        H[6] = dppf<0x141>(H[2]);
        H[7] = dppf<0x141>(H[3]);

        float gh[3];
#pragma unroll
        for (int qg = 0; qg < 3; ++qg) {
            float a = fmaf(whh[qg][1], H[1], whh[qg][0] * H[0]);
            a = fmaf(whh[qg][2], H[2], a);
            a = fmaf(whh[qg][3], H[3], a);
            // n-gate: seed with bhn so r multiplies (hn + b_hh_n), per reference
            float c = (qg == 2) ? fmaf(whh[qg][4], H[4], bhn)
                                : whh[qg][4] * H[4];
            c = fmaf(whh[qg][5], H[5], c);
            c = fmaf(whh[qg][6], H[6], c);
            c = fmaf(whh[qg][7], H[7], c);
            gh[qg] = a + c;
        }
        // weights pre-scaled: r,z rows by -log2e; n rows by +2log2e
        const float r  = rcp_fast(1.0f + exp2_fast(gx[0] + gh[0]));
        const float z  = rcp_fast(1.0f + exp2_fast(gx[1] + gh[1]));
        const float zh = z * h;
        const float om = 1.0f - z;
        const float e  = exp2_fast(fmaf(r, gh[2], gx[2]));
        const float n  = fmaf(-2.0f, rcp_fast(e + 1.0f), 1.0f);  // tanh
        h = fmaf(n, om, zh);
        __builtin_nontemporal_store(h, op + (size_t)t * (Gn * Hn));
    };

    // ---- pipeline: 8-deep ring of per-lane x pairs; proj 2 steps ahead ----
    v2f   xr[8];        // slot k holds this lane's pair for step (k mod ring)
    float gx[4][3];     // gx ring: step(s) reads s&3, proj writes (s+2)&3

    {
        v2f t0 = load_x(0);
        v2f t1 = load_x(1);
        xr[2] = load_x(2); xr[3] = load_x(3); xr[4] = load_x(4);
        xr[5] = load_x(5); xr[6] = load_x(6); xr[7] = load_x(7);
        proj(t0, gx[0]);  // gx for step 0
        proj(t1, gx[1]);  // gx for step 1
    }

    for (int t = 0; t < Tn; t += 8) {
#pragma unroll
        for (int j = 0; j < 8; ++j) {
            const int s = t + j;
            int tl = s + 8; if (tl > Tn - 1) tl = Tn - 1;
            xr[j] = load_x(tl);           // x for step s+8, in flight 6 bodies
            // pin slot (j+2)&7 (loaded 6 bodies ago -> vmcnt wait is free);
            // single operand, blocks remat/sink of the consumed slot.
            asm volatile("" : "+v"(xr[(j + 2) & 7]));
            proj(xr[(j + 2) & 7], gx[(j + 2) & 3]);  // gx for step s+2
            step(gx[j & 3], s);           // recurrent chain for step s
        }
    }
}

extern "C" void kernel_launch(void* const* d_in, const int* in_sizes, int n_in,
                              void* d_out, int out_size, void* d_ws, size_t ws_size,
                              hipStream_t stream) {
    const float* x    = (const float*)d_in[0];
    const float* W_ih = (const float*)d_in[1];
    const float* W_hh = (const float*)d_in[2];
    const float* b_ih = (const float*)d_in[3];
    const float* b_hh = (const float*)d_in[4];
    float* out = (float*)d_out;

    // 4096 cells * 8 lanes = 512 waves; 1 wave/block over 256 CUs.
    dim3 grid(512), block(64);
    hipLaunchKernelGGL(mcgru_kernel, grid, block, 0, stream,
                       x, W_ih, W_hh, b_ih, b_hh, out);
}

// Round 5
// 278.764 us; speedup vs baseline: 1.0375x; 1.0375x over previous
//
#include <hip/hip_runtime.h>

// Grouped GRU: G=64, D=16, H=8, B=64, T=512. R11: SPLIT-K, 16 lanes/cell.
// (R12 = R11 resubmitted verbatim: round-4 bench failed at GPU acquisition,
// kernel never ran. Lane algebra re-audited: proj slot k = x[8p+(u^m[k])],
// gh halves p=0:{0,1,2,3} / p=1:{7,6,5,4} via px fold, row_ror:8 pair-sum,
// biases seeded once on p==0.x, b_hh_n inside r*(...). All DPP within the
// 16-lane row.)
//
// Evidence through R10: three different kernels (R8/R9/R10) all pin VALUBusy
// at 35-36%; R10 removed register pressure (VGPR 132) yet got SLOWER by ~the
// instruction count it added (16 DPPs) => per-wave time tracks the per-step
// instruction stream, stalls are chain/trans latency the leftover independent
// work can't cover. Wall = 512 serial steps x one wave's per-step time; with
// 512 waves on 1024 SIMDs co-residency can't help. Only lever: shorten the
// stream.
// Change: 16 lanes/cell (u=unit, p=K-half). Per lane: proj = 4 pk_fma/gate
// over its 8 x-elems; gh = 2 pk_fma/gate over its 4 H-terms; halves summed
// with ONE v_add_f32 row_ror:8 per gate (pair l<->l^8 is inside a DPP row).
// x: 4B/lane (wave = 256B contiguous). Gates duplicated across the pair
// (SIMD-free). Biases folded as pk-acc seeds on p==0 lane; b_hh_n seeds gh_n
// so r multiplies (hn + b_hh_n) — R7 semantics preserved. Waves 512 -> 1024:
// every SIMD now hosts a wave. Per-step VALU ~118 -> ~60.
// Predicted: VGPR ~100, Occupancy ~11%, dispatch 140 -> 85-110 us.
// VALUBusy is the normalization diagnostic: ~35% (per-active) vs ~60%+
// (per-all-SIMD).
//
// Carried: 8-deep per-lane x ring, proj 2 steps ahead, single ring pin;
// gate scales pre-folded (-log2e for r,z; +2log2e for n); exp2/rcp gates.

#define Gn 64
#define Dn 16
#define Hn 8
#define Tn 512

typedef float v2f __attribute__((ext_vector_type(2)));

__device__ __forceinline__ float rcp_fast(float v) { return __builtin_amdgcn_rcpf(v); }
__device__ __forceinline__ float exp2_fast(float v) { return __builtin_amdgcn_exp2f(v); }

#define KNL (-1.44269504088896340736f)   // -log2(e)
#define KP2 ( 2.88539008177792681472f)   // +2*log2(e)

template <int CTRL>
__device__ __forceinline__ float dppf(float v) {
    return __int_as_float(
        __builtin_amdgcn_update_dpp(0, __float_as_int(v), CTRL, 0xF, 0xF, false));
}

__global__ __attribute__((amdgpu_flat_work_group_size(64, 64),
                          amdgpu_waves_per_eu(1, 1)))
void mcgru_kernel(
    const float* __restrict__ x,     // [B, T, G*D]
    const float* __restrict__ W_ih,  // [G, 3H, D]
    const float* __restrict__ W_hh,  // [G, 3H, H]
    const float* __restrict__ b_ih,  // [G, 3H]
    const float* __restrict__ b_hh,  // [G, 3H]
    float* __restrict__ out)         // [B, T, G, H]
{
    const int lane  = threadIdx.x;       // 0..63
    const int row16 = lane >> 4;         // cell slot within wave (DPP row)
    const int il    = lane & 15;         // lane within cell
    const int u     = il & 7;            // hidden unit
    const int p     = il >> 3;           // K-half (0: first 8, 1: last 8)
    const int cell  = blockIdx.x * 4 + row16;
    const int g     = cell & (Gn - 1);
    const int b     = cell >> 6;

    // DPP slot masks for 8-wide gathers (quad_perm xor1/2/3 + half-mirror):
    // slot k delivers value from half-row lane u ^ m[k].
    const int m[8] = {0, 1, 2, 3, 7, 6, 5, 4};
    const int px   = p ? 7 : 0;          // h-gather slot mask offset for p=1

    const float scale[3] = {KNL, KNL, KP2};

    // ---- preload weights, pre-scaled, gather-order permuted ----
    v2f wihp[3][4];   // proj weight pairs: pair j = (w[8p+(u^m2j)], w[8p+(u^m2j1)])
    v2f whhp[3][2];   // gh weight pairs:  pair j = (w[u^(2j^px)], w[u^(2j+1^px)])
    v2f bsv[3];       // proj pk-acc seed: bias on p==0 lane's .x, else 0
    v2f ghs;          // gh_n pk-acc seed: b_hh_n*KP2 on p==0 .x (inside r*(...))
#pragma unroll
    for (int qg = 0; qg < 3; ++qg) {
        const int row = qg * Hn + u;
        const float sc = scale[qg];
        const float* wr = W_ih + ((size_t)g * 24 + row) * Dn + 8 * p;
#pragma unroll
        for (int j = 0; j < 4; ++j) {
            wihp[qg][j] = (v2f){wr[u ^ m[2 * j]] * sc, wr[u ^ m[2 * j + 1]] * sc};
        }
        const float* hr = W_hh + ((size_t)g * 24 + row) * Hn;
#pragma unroll
        for (int j = 0; j < 2; ++j) {
            whhp[qg][j] = (v2f){hr[u ^ ((2 * j) ^ px)] * sc,
                                hr[u ^ ((2 * j + 1) ^ px)] * sc};
        }
        float bias;
        if (qg < 2) bias = (b_ih[g * 24 + row] + b_hh[g * 24 + row]) * sc;
        else        bias = b_ih[g * 24 + row] * sc;      // n: input-side only
        bsv[qg] = (p == 0) ? (v2f){bias, 0.0f} : (v2f){0.0f, 0.0f};
    }
    ghs = (p == 0) ? (v2f){b_hh[g * 24 + 16 + u] * KP2, 0.0f}
                   : (v2f){0.0f, 0.0f};

    // Pin loop-invariants: no remat/sink into the T loop.
#pragma unroll
    for (int qg = 0; qg < 3; ++qg) {
#pragma unroll
        for (int j = 0; j < 4; ++j) asm volatile("" : "+v"(wihp[qg][j]));
#pragma unroll
        for (int j = 0; j < 2; ++j) asm volatile("" : "+v"(whhp[qg][j]));
        asm volatile("" : "+v"(bsv[qg]));
    }
    asm volatile("" : "+v"(ghs));

    // Per-lane x: 1 float/step (wave = 256B contiguous).
    const float* xq = x   + ((size_t)b * Tn * (Gn * Dn)) + g * Dn + il;
    float*       op = out + ((size_t)b * Tn * (Gn * Hn)) + g * Hn + u;

    auto load_x = [&](int t) -> float { return xq[(size_t)t * (Gn * Dn)]; };

    // proj: gather the half-row's 8 x-elems via DPP, 4 pk_fma/gate, pair-sum.
    auto proj = [&](float xv, float* gx) {
        float X1 = dppf<0xB1>(xv);
        float X2 = dppf<0x4E>(xv);
        float X3 = dppf<0x1B>(xv);
        v2f P0, P1, P2, P3;
        P0.x = xv;              P0.y = X1;
        P1.x = X2;              P1.y = X3;
        P2.x = dppf<0x141>(xv); P2.y = dppf<0x141>(X1);
        P3.x = dppf<0x141>(X2); P3.y = dppf<0x141>(X3);
#pragma unroll
        for (int qg = 0; qg < 3; ++qg) {
            v2f acc = wihp[qg][0] * P0 + bsv[qg];  // v_pk_fma_f32, bias seeded
            acc = wihp[qg][1] * P1 + acc;
            acc = wihp[qg][2] * P2 + acc;
            acc = wihp[qg][3] * P3 + acc;
            float part = acc.x + acc.y;
            gx[qg] = dppf<0x128>(part) + part;     // + partner half (row_ror:8)
        }
    };

    float h = 0.0f;
    float gh[3];
    // step head: H-gather (3 DPP levels) + 2 pk_fma/gate + pair-sum.
    auto step_head = [&]() {
        const float M = dppf<0x141>(h);   // half-mirror: h[u^7]
        const float B = p ? M : h;        // p=0 slots {0..3}, p=1 slots {7..4}
        v2f Hp0, Hp1;
        Hp0.x = B;
        Hp0.y = dppf<0xB1>(B);
        Hp1.x = dppf<0x4E>(B);
        Hp1.y = dppf<0x1B>(B);
#pragma unroll
        for (int qg = 0; qg < 3; ++qg) {
            v2f acc = (qg == 2) ? (whhp[qg][0] * Hp0 + ghs)   // r*(hn+b_hh_n)
                                : (whhp[qg][0] * Hp0);
            acc = whhp[qg][1] * Hp1 + acc;
            float part = acc.x + acc.y;
            gh[qg] = dppf<0x128>(part) + part;     // full H-dot on both halves
        }
    };
    // step tail: gates (duplicated across the pair), h update, store (p==0).
    auto step_tail = [&](const float* gx, int t) {
        const float r  = rcp_fast(1.0f + exp2_fast(gx[0] + gh[0]));
        const float z  = rcp_fast(1.0f + exp2_fast(gx[1] + gh[1]));
        const float zh = z * h;
        const float om = 1.0f - z;
        const float e  = exp2_fast(fmaf(r, gh[2], gx[2]));
        const float n  = fmaf(-2.0f, rcp_fast(e + 1.0f), 1.0f);  // tanh
        h = fmaf(n, om, zh);
        if (p == 0)
            __builtin_nontemporal_store(h, op + (size_t)t * (Gn * Hn));
    };

    // ---- pipeline: 8-deep ring of per-lane x floats; proj 2 steps ahead ----
    float xr[8];
    float gx[4][3];
    {
        float t0 = load_x(0);
        float t1 = load_x(1);
        xr[2] = load_x(2); xr[3] = load_x(3); xr[4] = load_x(4);
        xr[5] = load_x(5); xr[6] = load_x(6); xr[7] = load_x(7);
        proj(t0, gx[0]);
        proj(t1, gx[1]);
    }

    for (int t = 0; t < Tn; t += 8) {
#pragma unroll
        for (int j = 0; j < 8; ++j) {
            const int s = t + j;
            int tl = s + 8; if (tl > Tn - 1) tl = Tn - 1;
            xr[j] = load_x(tl);                // x for step s+8
            asm volatile("" : "+v"(xr[(j + 2) & 7]));  // anchor consumed slot
            step_head();                       // gh chain head for step s
            proj(xr[(j + 2) & 7], gx[(j + 2) & 3]);  // filler: gx for s+2
            step_tail(gx[j & 3], s);           // gates + h update for step s
        }
    }
}

extern "C" void kernel_launch(void* const* d_in, const int* in_sizes, int n_in,
                              void* d_out, int out_size, void* d_ws, size_t ws_size,
                              hipStream_t stream) {
    const float* x    = (const float*)d_in[0];
    const float* W_ih = (const float*)d_in[1];
    const float* W_hh = (const float*)d_in[2];
    const float* b_ih = (const float*)d_in[3];
    const float* b_hh = (const float*)d_in[4];
    float* out = (float*)d_out;

    // 4096 cells * 16 lanes = 1024 waves; 1 wave/block, all 1024 SIMDs active.
    dim3 grid(1024), block(64);
    hipLaunchKernelGGL(mcgru_kernel, grid, block, 0, stream,
                       x, W_ih, W_hh, b_ih, b_hh, out);
}